// Round 6
// baseline (498.322 us; speedup 1.0000x reference)
//
#include <hip/hip_runtime.h>
#include <hip/hip_bf16.h>
#include <stdint.h>

typedef __attribute__((ext_vector_type(4))) float f32x4;
typedef __attribute__((ext_vector_type(8))) short bf16x8;

#define NDIM 6
#define IN_DIM 256
#define OUT_DIM 256
#define KW 780          // W inner dim (256*3 + 6*2)
#define NR 262          // node_rep row (256+6)
#define NRP 320         // padded node_rep row: 5 x 64-k tiles for P-GEMM
#define SCAN_T 1024

__device__ __forceinline__ short f2bf(float f) {
  return __builtin_bit_cast(short, __float2bfloat16(f));
}

__device__ __forceinline__ void gload_lds16(void* lds, const void* g) {
  __builtin_amdgcn_global_load_lds(
      (const __attribute__((address_space(1))) unsigned int*)g,
      (__attribute__((address_space(3))) unsigned int*)lds, 16, 0, 0);
}

// ---------------- CSR build ----------------
__global__ void hist_kernel(const int* __restrict__ ei, int* __restrict__ counts, int E) {
  int e = blockIdx.x * 256 + threadIdx.x;
  if (e < E) atomicAdd(&counts[ei[(long)E + e]], 1);
}

__global__ __launch_bounds__(SCAN_T) void scan_kernel(const int* __restrict__ counts,
                                                      int* __restrict__ offsets, int N) {
  __shared__ int part[SCAN_T];
  int t = threadIdx.x;
  int chunk = (N + SCAN_T - 1) / SCAN_T;
  int begin = t * chunk;
  int s = 0;
  for (int i = 0; i < chunk; ++i) {
    int idx = begin + i;
    if (idx < N) s += counts[idx];
  }
  part[t] = s;
  __syncthreads();
  for (int d = 1; d < SCAN_T; d <<= 1) {
    int v = (t >= d) ? part[t - d] : 0;
    __syncthreads();
    part[t] += v;
    __syncthreads();
  }
  int run = (t == 0) ? 0 : part[t - 1];
  for (int i = 0; i < chunk; ++i) {
    int idx = begin + i;
    if (idx < N) { offsets[idx] = run; run += counts[idx]; }
  }
}

__global__ void scatter_kernel(const int* __restrict__ ei, const int* __restrict__ offsets,
                               int* __restrict__ cursor, int* __restrict__ csr, int E) {
  int e = blockIdx.x * 256 + threadIdx.x;
  if (e >= E) return;
  int col = ei[(long)E + e];
  int pos = atomicAdd(&cursor[col], 1);
  csr[offsets[col] + pos] = e;
}

// ------- gather-reduce per node + node_rep emit (f32 out + bf16 copy) -------
// one wave per node; csr/mask routed through the scalar pipe (wave-uniform)
__global__ __launch_bounds__(256) void reduce_kernel(
    const int* __restrict__ csr, const int* __restrict__ offsets,
    const int* __restrict__ counts, const float* __restrict__ ea,
    const float* __restrict__ mask, const float* __restrict__ x,
    float* __restrict__ outN, short* __restrict__ nrepb, int N) {
  int n = blockIdx.x * 4 + (threadIdx.x >> 6);
  if (n >= N) return;
  int lane = threadIdx.x & 63;
  int s = __builtin_amdgcn_readfirstlane(offsets[n]);
  int cnt = __builtin_amdgcn_readfirstlane(counts[n]);
  f32x4 sum = (f32x4)0.0f;
  float den = 0.0f;
#pragma unroll 8
  for (int i = 0; i < cnt; ++i) {
    int e = __builtin_amdgcn_readfirstlane(csr[s + i]);   // SGPR edge id
    float m = mask[e];                                    // uniform addr
    den += m;
    f32x4 v = ((const f32x4*)ea)[(long)e * 64 + lane];
    sum.x += v.x * m; sum.y += v.y * m; sum.z += v.z * m; sum.w += v.w * m;
  }
  float inv = 1.0f / (den + 1.0f);
  sum.x *= inv; sum.y *= inv; sum.z *= inv; sum.w *= inv;
  float* po = outN + (long)n * NR + lane * 4;
  po[0] = sum.x; po[1] = sum.y; po[2] = sum.z; po[3] = sum.w;
  short4 pb;
  pb.x = f2bf(sum.x); pb.y = f2bf(sum.y); pb.z = f2bf(sum.z); pb.w = f2bf(sum.w);
  *(short4*)(nrepb + (long)n * NRP + lane * 4) = pb;
  if (lane < NDIM) {
    float xv = x[(long)n * NDIM + lane];
    outN[(long)n * NR + IN_DIM + lane] = xv;
    nrepb[(long)n * NRP + IN_DIM + lane] = f2bf(xv);
  } else if (lane < 8) {
    nrepb[(long)n * NRP + IN_DIM + lane] = 0;  // cols 262,263 -> 0
  }
  // cols 264..319 untouched; W pad columns are 0 so their product is 0
}

// -------- W -> bf16 splits: Weat [256][256], Wrt/Wct [256][320] (pad 0) -----
__global__ void wprep_kernel(const float* __restrict__ W, short* __restrict__ Weat,
                             short* __restrict__ Wrt, short* __restrict__ Wct) {
  int idx = blockIdx.x * 256 + threadIdx.x;
  if (idx < OUT_DIM * 256) {
    int n = idx >> 8, k = idx & 255;
    Weat[idx] = f2bf(W[(long)n * KW + 2 * NR + k]);
    return;
  }
  idx -= OUT_DIM * 256;
  if (idx < OUT_DIM * NRP) {
    int n = idx / NRP, k = idx % NRP;
    Wrt[idx] = f2bf(k < NR ? W[(long)n * KW + k] : 0.0f);
    return;
  }
  idx -= OUT_DIM * NRP;
  if (idx < OUT_DIM * NRP) {
    int n = idx / NRP, k = idx % NRP;
    Wct[idx] = f2bf(k < NR ? W[(long)n * KW + NR + k] : 0.0f);
  }
}

// ---------------- P-GEMM: P_r = nrep@Wr^T + b ; P_c = nrep@Wc^T -------------
__global__ __launch_bounds__(256, 2) void pgemm_kernel(
    const short* __restrict__ nrepb, const short* __restrict__ Wrt,
    const short* __restrict__ Wct, const float* __restrict__ bias,
    float* __restrict__ Pr, float* __restrict__ Pc, int N) {
  __shared__ short As[5][64 * 64];   // 40 KB
  const int tid = threadIdx.x;
  const int wave = tid >> 6, lane = tid & 63;
  const int m0 = blockIdx.x * 64;
  const int table = blockIdx.y;
  const short* Wt = table ? Wct : Wrt;
  float* P = table ? Pc : Pr;
  const int nbase = wave * 64;

  float bvals[4];
#pragma unroll
  for (int nf = 0; nf < 4; ++nf)
    bvals[nf] = table ? 0.0f : bias[nbase + 16 * nf + (lane & 15)];

  f32x4 acc[4][4];
#pragma unroll
  for (int mf = 0; mf < 4; ++mf)
#pragma unroll
    for (int nf = 0; nf < 4; ++nf) acc[mf][nf] = (f32x4)0.0f;

  bf16x8 bv[2][8];
  auto loadB = [&](int t, int tb) {
#pragma unroll
    for (int s2 = 0; s2 < 2; ++s2)
#pragma unroll
      for (int nf = 0; nf < 4; ++nf)
        bv[tb][s2 * 4 + nf] = *(const bf16x8*)&Wt[
            (long)(nbase + nf * 16 + (lane & 15)) * NRP + t * 64 + s2 * 32 + (lane >> 4) * 8];
  };

  const int scp = lane & 7;
#pragma unroll
  for (int t = 0; t < 5; ++t)
#pragma unroll
    for (int i = 0; i < 2; ++i) {
      int row = 16 * wave + 8 * i + (lane >> 3);
      int c = scp ^ (row & 7);
      long m = m0 + row; if (m >= N) m = N - 1;
      gload_lds16(&As[t][(16 * wave + 8 * i) * 64], nrepb + m * NRP + t * 64 + 8 * c);
    }
  loadB(0, 0);
  asm volatile("s_waitcnt vmcnt(8)" ::: "memory");   // A landed; B0 in flight
  __builtin_amdgcn_s_barrier();
  __builtin_amdgcn_sched_barrier(0);

#pragma unroll
  for (int t = 0; t < 5; ++t) {
    if (t < 4) loadB(t + 1, (t + 1) & 1);
    if (t < 4) asm volatile("s_waitcnt vmcnt(8)" ::: "memory");
    else       asm volatile("s_waitcnt vmcnt(0)" ::: "memory");
#pragma unroll
    for (int s2 = 0; s2 < 2; ++s2) {
      bf16x8 a[4];
      int cl = s2 * 4 + (lane >> 4);
#pragma unroll
      for (int mf = 0; mf < 4; ++mf) {
        int m = 16 * mf + (lane & 15);
        a[mf] = *(const bf16x8*)&As[t][m * 64 + ((cl ^ (m & 7)) * 8)];
      }
#pragma unroll
      for (int mf = 0; mf < 4; ++mf)
#pragma unroll
        for (int nf = 0; nf < 4; ++nf)
          acc[mf][nf] = __builtin_amdgcn_mfma_f32_16x16x32_bf16(
              a[mf], bv[t & 1][s2 * 4 + nf], acc[mf][nf], 0, 0, 0);
    }
  }

#pragma unroll
  for (int mf = 0; mf < 4; ++mf)
#pragma unroll
    for (int nf = 0; nf < 4; ++nf)
#pragma unroll
      for (int q = 0; q < 4; ++q) {
        long m = m0 + 16 * mf + (lane >> 4) * 4 + q;
        if (m < N)
          P[m * OUT_DIM + nbase + 16 * nf + (lane & 15)] = acc[mf][nf][q] + bvals[nf];
      }
}

// ------ edge GEMM: out[e] = ea[e]@Weat^T + Pr[row[e]] + Pc[col[e]] ----------
// BM=128, 512 threads (2m x 4n waves). A staged once (f32->bf16), ONE barrier,
// no in-loop barriers; B per-wave reg dbuf from L2; P-add fused in epilogue.
__global__ __launch_bounds__(512, 4) void egemm_kernel(
    const int* __restrict__ ei, const float* __restrict__ ea,
    const short* __restrict__ Weat, const float* __restrict__ Pr,
    const float* __restrict__ Pc, float* __restrict__ outE, int E) {
  __shared__ short As[4][128 * 64];   // 64 KB
  const int tid = threadIdx.x;
  const int wave = tid >> 6, lane = tid & 63;
  const long e0 = (long)blockIdx.x * 128;
  const int wm = wave >> 2, wn = wave & 3;
  const int mbase = wm * 64, nbase = wn * 64;

  f32x4 acc[4][4];
#pragma unroll
  for (int mf = 0; mf < 4; ++mf)
#pragma unroll
    for (int nf = 0; nf < 4; ++nf) acc[mf][nf] = (f32x4)0.0f;

  bf16x8 bv[2][8];
  auto loadB = [&](int t, int tb) {
#pragma unroll
    for (int s2 = 0; s2 < 2; ++s2)
#pragma unroll
      for (int nf = 0; nf < 4; ++nf)
        bv[tb][s2 * 4 + nf] = *(const bf16x8*)&Weat[
            (nbase + nf * 16 + (lane & 15)) * 256 + t * 64 + s2 * 32 + (lane >> 4) * 8];
  };

  // ---- stage all 4 A-tiles: 128 rows x 256 k, f32 -> bf16, swizzled writes ----
  f32x4 eh[8][2];
#pragma unroll
  for (int j = 0; j < 8; ++j) {
    int c8 = tid + j * 512;                 // bf16x8-chunk index in 128x256 tile
    int row = c8 >> 5, cp8 = c8 & 31;
    long e = e0 + row; if (e >= E) e = E - 1;
    const f32x4* s = (const f32x4*)(ea + (e * IN_DIM + cp8 * 8));
    eh[j][0] = s[0];
    eh[j][1] = s[1];
  }
  loadB(0, 0);
  __builtin_amdgcn_sched_barrier(0);        // pin: all issues above, converts below
#pragma unroll
  for (int j = 0; j < 8; ++j) {
    int c8 = tid + j * 512;
    int row = c8 >> 5, cp8 = c8 & 31;
    int t = cp8 >> 3, cp = cp8 & 7;
    f32x4 v0 = eh[j][0], v1 = eh[j][1];
    bf16x8 p;
    p[0] = f2bf(v0.x); p[1] = f2bf(v0.y); p[2] = f2bf(v0.z); p[3] = f2bf(v0.w);
    p[4] = f2bf(v1.x); p[5] = f2bf(v1.y); p[6] = f2bf(v1.z); p[7] = f2bf(v1.w);
    *(bf16x8*)&As[t][row * 64 + ((cp ^ (row & 7)) * 8)] = p;
  }
  asm volatile("s_waitcnt lgkmcnt(0)" ::: "memory");
  __builtin_amdgcn_s_barrier();             // B0 stays in flight (no vmcnt drain)
  __builtin_amdgcn_sched_barrier(0);

  // ---- 4 tiles, no barriers (LDS read-only after), counted vmcnt on B dbuf ----
#pragma unroll
  for (int t = 0; t < 4; ++t) {
    if (t < 3) loadB(t + 1, (t + 1) & 1);
    if (t < 3) asm volatile("s_waitcnt vmcnt(8)" ::: "memory");
    else       asm volatile("s_waitcnt vmcnt(0)" ::: "memory");
#pragma unroll
    for (int s2 = 0; s2 < 2; ++s2) {
      bf16x8 a[4];
      int cl = s2 * 4 + (lane >> 4);
#pragma unroll
      for (int mf = 0; mf < 4; ++mf) {
        int m = mbase + 16 * mf + (lane & 15);
        a[mf] = *(const bf16x8*)&As[t][m * 64 + ((cl ^ (m & 7)) * 8)];
      }
#pragma unroll
      for (int mf = 0; mf < 4; ++mf)
#pragma unroll
        for (int nf = 0; nf < 4; ++nf)
          acc[mf][nf] = __builtin_amdgcn_mfma_f32_16x16x32_bf16(
              a[mf], bv[t & 1][s2 * 4 + nf], acc[mf][nf], 0, 0, 0);
    }
  }

  // ---- epilogue: + Pr[row[e]][n] + Pc[col[e]][n], store ----
#pragma unroll
  for (int mf = 0; mf < 4; ++mf) {
#pragma unroll
    for (int q = 0; q < 4; ++q) {
      long e = e0 + mbase + 16 * mf + (lane >> 4) * 4 + q;
      bool ok = e < E;
      long ec = ok ? e : (E - 1);
      int re = ei[ec], ce = ei[(long)E + ec];
      const float* pr = Pr + (long)re * OUT_DIM;
      const float* pc = Pc + (long)ce * OUT_DIM;
      if (ok) {
#pragma unroll
        for (int nf = 0; nf < 4; ++nf) {
          int n = nbase + 16 * nf + (lane & 15);
          outE[e * OUT_DIM + n] = acc[mf][nf][q] + pr[n] + pc[n];
        }
      }
    }
  }
}

extern "C" void kernel_launch(void* const* d_in, const int* in_sizes, int n_in,
                              void* d_out, int out_size, void* d_ws, size_t ws_size,
                              hipStream_t stream) {
  const float* x    = (const float*)d_in[0];
  const int*   ei   = (const int*)d_in[2];
  const float* ea   = (const float*)d_in[3];
  const float* mask = (const float*)d_in[4];
  const float* W    = (const float*)d_in[5];
  const float* b    = (const float*)d_in[6];
  const int E = in_sizes[4];
  const int N = in_sizes[0] / NDIM;

  // ws layout
  char* p = (char*)d_ws;
  int* counts  = (int*)p; p += (long)N * 4;
  int* cursor  = (int*)p; p += (long)N * 4;
  int* offsets = (int*)p; p += (long)(N + 1) * 4;
  int* csr     = (int*)p; p += (long)E * 4;
  p = (char*)(((uintptr_t)p + 15) & ~(uintptr_t)15);
  short* nrepb = (short*)p; p += (long)N * NRP * 2;
  short* Weat  = (short*)p; p += (long)OUT_DIM * 256 * 2;
  short* Wrt   = (short*)p; p += (long)OUT_DIM * NRP * 2;
  short* Wct   = (short*)p; p += (long)OUT_DIM * NRP * 2;
  float* Pr    = (float*)p; p += (long)N * OUT_DIM * 4;
  float* Pc    = (float*)p;

  float* outN = (float*)d_out;
  float* outE = outN + (long)N * NR;

  hipMemsetAsync(counts, 0, (size_t)2 * N * 4, stream);   // counts + cursor

  hist_kernel<<<(E + 255) / 256, 256, 0, stream>>>(ei, counts, E);
  scan_kernel<<<1, SCAN_T, 0, stream>>>(counts, offsets, N);
  scatter_kernel<<<(E + 255) / 256, 256, 0, stream>>>(ei, offsets, cursor, csr, E);
  reduce_kernel<<<(N + 3) / 4, 256, 0, stream>>>(csr, offsets, counts, ea, mask, x,
                                                 outN, nrepb, N);
  int wtot = OUT_DIM * 256 + 2 * OUT_DIM * NRP;
  wprep_kernel<<<(wtot + 255) / 256, 256, 0, stream>>>(W, Weat, Wrt, Wct);
  dim3 pg((N + 63) / 64, 2);
  pgemm_kernel<<<pg, 256, 0, stream>>>(nrepb, Wrt, Wct, b, Pr, Pc, N);
  egemm_kernel<<<(E + 127) / 128, 512, 0, stream>>>(ei, ea, Weat, Pr, Pc, outE, E);
}

// Round 7
// 383.672 us; speedup vs baseline: 1.2988x; 1.2988x over previous
//
#include <hip/hip_runtime.h>
#include <hip/hip_bf16.h>
#include <stdint.h>

typedef __attribute__((ext_vector_type(4))) float f32x4;
typedef __attribute__((ext_vector_type(8))) short bf16x8;

#define NDIM 6
#define IN_DIM 256
#define OUT_DIM 256
#define KW 780          // W inner dim (256*3 + 6*2)
#define NR 262          // node_rep row (256+6)
#define NRP 320         // padded node_rep row: 5 x 64-k tiles for P-GEMM
#define SCAN_T 1024

__device__ __forceinline__ short f2bf(float f) {
  return __builtin_bit_cast(short, __float2bfloat16(f));
}
__device__ __forceinline__ float bf2f(short h) {
  unsigned int u = ((unsigned int)(unsigned short)h) << 16;
  return __builtin_bit_cast(float, u);
}

__device__ __forceinline__ void gload_lds16(void* lds, const void* g) {
  __builtin_amdgcn_global_load_lds(
      (const __attribute__((address_space(1))) unsigned int*)g,
      (__attribute__((address_space(3))) unsigned int*)lds, 16, 0, 0);
}

// ---------------- CSR build ----------------
__global__ void hist_kernel(const int* __restrict__ ei, int* __restrict__ counts, int E) {
  int e = blockIdx.x * 256 + threadIdx.x;
  if (e < E) atomicAdd(&counts[ei[(long)E + e]], 1);
}

__global__ __launch_bounds__(SCAN_T) void scan_kernel(const int* __restrict__ counts,
                                                      int* __restrict__ offsets, int N) {
  __shared__ int part[SCAN_T];
  int t = threadIdx.x;
  int chunk = (N + SCAN_T - 1) / SCAN_T;
  int begin = t * chunk;
  int s = 0;
  for (int i = 0; i < chunk; ++i) {
    int idx = begin + i;
    if (idx < N) s += counts[idx];
  }
  part[t] = s;
  __syncthreads();
  for (int d = 1; d < SCAN_T; d <<= 1) {
    int v = (t >= d) ? part[t - d] : 0;
    __syncthreads();
    part[t] += v;
    __syncthreads();
  }
  int run = (t == 0) ? 0 : part[t - 1];
  for (int i = 0; i < chunk; ++i) {
    int idx = begin + i;
    if (idx < N) { offsets[idx] = run; run += counts[idx]; }
  }
}

__global__ void scatter_kernel(const int* __restrict__ ei, const int* __restrict__ offsets,
                               int* __restrict__ cursor, int* __restrict__ csr, int E) {
  int e = blockIdx.x * 256 + threadIdx.x;
  if (e >= E) return;
  int col = ei[(long)E + e];
  int pos = atomicAdd(&cursor[col], 1);
  csr[offsets[col] + pos] = e;
}

// ------- gather-reduce per node + node_rep emit (f32 out + bf16 copy) -------
// one wave per node. Per 64-edge chunk: ONE coalesced csr load + ONE mask
// gather (prefetched a chunk ahead); readlane broadcasts e/m to SGPRs, so the
// ea row loads are independent saddr loads — no per-edge VMEM chain.
__global__ __launch_bounds__(256) void reduce_kernel(
    const int* __restrict__ csr, const int* __restrict__ offsets,
    const int* __restrict__ counts, const float* __restrict__ ea,
    const float* __restrict__ mask, const float* __restrict__ x,
    float* __restrict__ outN, short* __restrict__ nrepb, int N) {
  int n = blockIdx.x * 4 + (threadIdx.x >> 6);
  if (n >= N) return;
  int lane = threadIdx.x & 63;
  int s = offsets[n], cnt = counts[n];
  f32x4 sum = (f32x4)0.0f;
  float den = 0.0f;

  int ecur = 0; float mcur = 0.0f;
  if (lane < cnt) { ecur = csr[s + lane]; mcur = mask[ecur]; }

  for (int base = 0; base < cnt; base += 64) {
    int enext = 0; float mnext = 0.0f;
    if (base + 64 < cnt) {                       // prefetch next chunk
      int idx = base + 64 + lane;
      if (idx < cnt) { enext = csr[s + idx]; mnext = mask[enext]; }
    }
    int mbits = __builtin_bit_cast(int, mcur);
#pragma unroll
    for (int i = 0; i < 64; ++i) {
      if (base + i >= cnt) break;                // uniform break
      int e = __builtin_amdgcn_readlane(ecur, i);
      float m = __builtin_bit_cast(float, __builtin_amdgcn_readlane(mbits, i));
      f32x4 v = ((const f32x4*)ea)[(long)e * 64 + lane];
      sum.x += v.x * m; sum.y += v.y * m; sum.z += v.z * m; sum.w += v.w * m;
      den += m;
    }
    ecur = enext; mcur = mnext;
  }

  float inv = 1.0f / (den + 1.0f);
  sum.x *= inv; sum.y *= inv; sum.z *= inv; sum.w *= inv;
  float* po = outN + (long)n * NR + lane * 4;
  po[0] = sum.x; po[1] = sum.y; po[2] = sum.z; po[3] = sum.w;
  short4 pb;
  pb.x = f2bf(sum.x); pb.y = f2bf(sum.y); pb.z = f2bf(sum.z); pb.w = f2bf(sum.w);
  *(short4*)(nrepb + (long)n * NRP + lane * 4) = pb;
  if (lane < NDIM) {
    float xv = x[(long)n * NDIM + lane];
    outN[(long)n * NR + IN_DIM + lane] = xv;
    nrepb[(long)n * NRP + IN_DIM + lane] = f2bf(xv);
  } else if (lane < 8) {
    nrepb[(long)n * NRP + IN_DIM + lane] = 0;  // cols 262,263 -> 0
  }
  // cols 264..319 untouched; W pad columns are 0 so their product is 0
}

// -------- W -> bf16 splits: Weat [256][256], Wrt/Wct [256][320] (pad 0) -----
__global__ void wprep_kernel(const float* __restrict__ W, short* __restrict__ Weat,
                             short* __restrict__ Wrt, short* __restrict__ Wct) {
  int idx = blockIdx.x * 256 + threadIdx.x;
  if (idx < OUT_DIM * 256) {
    int n = idx >> 8, k = idx & 255;
    Weat[idx] = f2bf(W[(long)n * KW + 2 * NR + k]);
    return;
  }
  idx -= OUT_DIM * 256;
  if (idx < OUT_DIM * NRP) {
    int n = idx / NRP, k = idx % NRP;
    Wrt[idx] = f2bf(k < NR ? W[(long)n * KW + k] : 0.0f);
    return;
  }
  idx -= OUT_DIM * NRP;
  if (idx < OUT_DIM * NRP) {
    int n = idx / NRP, k = idx % NRP;
    Wct[idx] = f2bf(k < NR ? W[(long)n * KW + NR + k] : 0.0f);
  }
}

// -------- P-GEMM: P_r = nrep@Wr^T + b ; P_c = nrep@Wc^T  (bf16 tables) ------
__global__ __launch_bounds__(256, 2) void pgemm_kernel(
    const short* __restrict__ nrepb, const short* __restrict__ Wrt,
    const short* __restrict__ Wct, const float* __restrict__ bias,
    short* __restrict__ Pr, short* __restrict__ Pc, int N) {
  __shared__ short As[5][64 * 64];   // 40 KB
  const int tid = threadIdx.x;
  const int wave = tid >> 6, lane = tid & 63;
  const int m0 = blockIdx.x * 64;
  const int table = blockIdx.y;
  const short* Wt = table ? Wct : Wrt;
  short* P = table ? Pc : Pr;
  const int nbase = wave * 64;

  float bvals[4];
#pragma unroll
  for (int nf = 0; nf < 4; ++nf)
    bvals[nf] = table ? 0.0f : bias[nbase + 16 * nf + (lane & 15)];

  f32x4 acc[4][4];
#pragma unroll
  for (int mf = 0; mf < 4; ++mf)
#pragma unroll
    for (int nf = 0; nf < 4; ++nf) acc[mf][nf] = (f32x4)0.0f;

  bf16x8 bv[2][8];
  auto loadB = [&](int t, int tb) {
#pragma unroll
    for (int s2 = 0; s2 < 2; ++s2)
#pragma unroll
      for (int nf = 0; nf < 4; ++nf)
        bv[tb][s2 * 4 + nf] = *(const bf16x8*)&Wt[
            (long)(nbase + nf * 16 + (lane & 15)) * NRP + t * 64 + s2 * 32 + (lane >> 4) * 8];
  };

  const int scp = lane & 7;
#pragma unroll
  for (int t = 0; t < 5; ++t)
#pragma unroll
    for (int i = 0; i < 2; ++i) {
      int row = 16 * wave + 8 * i + (lane >> 3);
      int c = scp ^ (row & 7);
      long m = m0 + row; if (m >= N) m = N - 1;
      gload_lds16(&As[t][(16 * wave + 8 * i) * 64], nrepb + m * NRP + t * 64 + 8 * c);
    }
  loadB(0, 0);
  asm volatile("s_waitcnt vmcnt(8)" ::: "memory");   // A landed; B0 in flight
  __builtin_amdgcn_s_barrier();
  __builtin_amdgcn_sched_barrier(0);

#pragma unroll
  for (int t = 0; t < 5; ++t) {
    if (t < 4) loadB(t + 1, (t + 1) & 1);
    if (t < 4) asm volatile("s_waitcnt vmcnt(8)" ::: "memory");
    else       asm volatile("s_waitcnt vmcnt(0)" ::: "memory");
#pragma unroll
    for (int s2 = 0; s2 < 2; ++s2) {
      bf16x8 a[4];
      int cl = s2 * 4 + (lane >> 4);
#pragma unroll
      for (int mf = 0; mf < 4; ++mf) {
        int m = 16 * mf + (lane & 15);
        a[mf] = *(const bf16x8*)&As[t][m * 64 + ((cl ^ (m & 7)) * 8)];
      }
#pragma unroll
      for (int mf = 0; mf < 4; ++mf)
#pragma unroll
        for (int nf = 0; nf < 4; ++nf)
          acc[mf][nf] = __builtin_amdgcn_mfma_f32_16x16x32_bf16(
              a[mf], bv[t & 1][s2 * 4 + nf], acc[mf][nf], 0, 0, 0);
    }
  }

#pragma unroll
  for (int mf = 0; mf < 4; ++mf)
#pragma unroll
    for (int nf = 0; nf < 4; ++nf)
#pragma unroll
      for (int q = 0; q < 4; ++q) {
        long m = m0 + 16 * mf + (lane >> 4) * 4 + q;
        if (m < N)
          P[m * OUT_DIM + nbase + 16 * nf + (lane & 15)] = f2bf(acc[mf][nf][q] + bvals[nf]);
      }
}

// ------ edge GEMM: out[e] = ea[e]@Weat^T + Pr[row[e]] + Pc[col[e]] ----------
// BM=64 (R5 structure: clean 320 MB WRITE). A staged once (f32->bf16), ONE
// barrier; B per-wave reg dbuf from L2; bf16 P-gather fused in epilogue.
__global__ __launch_bounds__(256, 2) void egemm_kernel(
    const int* __restrict__ ei, const float* __restrict__ ea,
    const short* __restrict__ Weat, const short* __restrict__ Pr,
    const short* __restrict__ Pc, float* __restrict__ outE, int E) {
  __shared__ short As[4][64 * 64];   // 32 KB
  const int tid = threadIdx.x;
  const int wave = tid >> 6, lane = tid & 63;
  const long e0 = (long)blockIdx.x * 64;
  const int nbase = wave * 64;

  f32x4 acc[4][4];
#pragma unroll
  for (int mf = 0; mf < 4; ++mf)
#pragma unroll
    for (int nf = 0; nf < 4; ++nf) acc[mf][nf] = (f32x4)0.0f;

  bf16x8 bv[2][8];
  auto loadB = [&](int t, int tb) {
#pragma unroll
    for (int s2 = 0; s2 < 2; ++s2)
#pragma unroll
      for (int nf = 0; nf < 4; ++nf)
        bv[tb][s2 * 4 + nf] = *(const bf16x8*)&Weat[
            (nbase + nf * 16 + (lane & 15)) * 256 + t * 64 + s2 * 32 + (lane >> 4) * 8];
  };

  // ---- stage all 4 A-tiles: 64 rows x 256 k, f32 -> bf16, swizzled writes ----
  f32x4 eh[8][2];
#pragma unroll
  for (int j = 0; j < 8; ++j) {
    int c8 = tid + j * 256;                 // bf16x8-chunk index in 64x256 tile
    int row = c8 >> 5, cp8 = c8 & 31;
    long e = e0 + row; if (e >= E) e = E - 1;
    const f32x4* s = (const f32x4*)(ea + (e * IN_DIM + cp8 * 8));
    eh[j][0] = s[0];
    eh[j][1] = s[1];
  }
  loadB(0, 0);
  __builtin_amdgcn_sched_barrier(0);        // pin: all issues above, converts below
#pragma unroll
  for (int j = 0; j < 8; ++j) {
    int c8 = tid + j * 256;
    int row = c8 >> 5, cp8 = c8 & 31;
    int t = cp8 >> 3, cp = cp8 & 7;
    f32x4 v0 = eh[j][0], v1 = eh[j][1];
    bf16x8 p;
    p[0] = f2bf(v0.x); p[1] = f2bf(v0.y); p[2] = f2bf(v0.z); p[3] = f2bf(v0.w);
    p[4] = f2bf(v1.x); p[5] = f2bf(v1.y); p[6] = f2bf(v1.z); p[7] = f2bf(v1.w);
    *(bf16x8*)&As[t][row * 64 + ((cp ^ (row & 7)) * 8)] = p;
  }
  asm volatile("s_waitcnt lgkmcnt(0)" ::: "memory");
  __builtin_amdgcn_s_barrier();             // B0 stays in flight (no vmcnt drain)
  __builtin_amdgcn_sched_barrier(0);

  // ---- 4 tiles, no barriers (LDS read-only after), counted vmcnt on B dbuf ----
#pragma unroll
  for (int t = 0; t < 4; ++t) {
    if (t < 3) loadB(t + 1, (t + 1) & 1);
    if (t < 3) asm volatile("s_waitcnt vmcnt(8)" ::: "memory");
    else       asm volatile("s_waitcnt vmcnt(0)" ::: "memory");
#pragma unroll
    for (int s2 = 0; s2 < 2; ++s2) {
      bf16x8 a[4];
      int cl = s2 * 4 + (lane >> 4);
#pragma unroll
      for (int mf = 0; mf < 4; ++mf) {
        int m = 16 * mf + (lane & 15);
        a[mf] = *(const bf16x8*)&As[t][m * 64 + ((cl ^ (m & 7)) * 8)];
      }
#pragma unroll
      for (int mf = 0; mf < 4; ++mf)
#pragma unroll
        for (int nf = 0; nf < 4; ++nf)
          acc[mf][nf] = __builtin_amdgcn_mfma_f32_16x16x32_bf16(
              a[mf], bv[t & 1][s2 * 4 + nf], acc[mf][nf], 0, 0, 0);
    }
  }

  // ---- epilogue: + Pr[row[e]][n] + Pc[col[e]][n] (bf16 tables), store ----
#pragma unroll
  for (int mf = 0; mf < 4; ++mf) {
#pragma unroll
    for (int q = 0; q < 4; ++q) {
      long e = e0 + 16 * mf + (lane >> 4) * 4 + q;
      bool ok = e < E;
      long ec = ok ? e : (E - 1);
      int re = ei[ec], ce = ei[(long)E + ec];
      const short* pr = Pr + (long)re * OUT_DIM;
      const short* pc = Pc + (long)ce * OUT_DIM;
      if (ok) {
#pragma unroll
        for (int nf = 0; nf < 4; ++nf) {
          int n = nbase + 16 * nf + (lane & 15);
          outE[e * OUT_DIM + n] = acc[mf][nf][q] + bf2f(pr[n]) + bf2f(pc[n]);
        }
      }
    }
  }
}

extern "C" void kernel_launch(void* const* d_in, const int* in_sizes, int n_in,
                              void* d_out, int out_size, void* d_ws, size_t ws_size,
                              hipStream_t stream) {
  const float* x    = (const float*)d_in[0];
  const int*   ei   = (const int*)d_in[2];
  const float* ea   = (const float*)d_in[3];
  const float* mask = (const float*)d_in[4];
  const float* W    = (const float*)d_in[5];
  const float* b    = (const float*)d_in[6];
  const int E = in_sizes[4];
  const int N = in_sizes[0] / NDIM;

  // ws layout
  char* p = (char*)d_ws;
  int* counts  = (int*)p; p += (long)N * 4;
  int* cursor  = (int*)p; p += (long)N * 4;
  int* offsets = (int*)p; p += (long)(N + 1) * 4;
  int* csr     = (int*)p; p += (long)E * 4;
  p = (char*)(((uintptr_t)p + 15) & ~(uintptr_t)15);
  short* nrepb = (short*)p; p += (long)N * NRP * 2;
  short* Weat  = (short*)p; p += (long)OUT_DIM * 256 * 2;
  short* Wrt   = (short*)p; p += (long)OUT_DIM * NRP * 2;
  short* Wct   = (short*)p; p += (long)OUT_DIM * NRP * 2;
  short* Pr    = (short*)p; p += (long)N * OUT_DIM * 2;
  short* Pc    = (short*)p;

  float* outN = (float*)d_out;
  float* outE = outN + (long)N * NR;

  hipMemsetAsync(counts, 0, (size_t)2 * N * 4, stream);   // counts + cursor

  hist_kernel<<<(E + 255) / 256, 256, 0, stream>>>(ei, counts, E);
  scan_kernel<<<1, SCAN_T, 0, stream>>>(counts, offsets, N);
  scatter_kernel<<<(E + 255) / 256, 256, 0, stream>>>(ei, offsets, cursor, csr, E);
  reduce_kernel<<<(N + 3) / 4, 256, 0, stream>>>(csr, offsets, counts, ea, mask, x,
                                                 outN, nrepb, N);
  int wtot = OUT_DIM * 256 + 2 * OUT_DIM * NRP;
  wprep_kernel<<<(wtot + 255) / 256, 256, 0, stream>>>(W, Weat, Wrt, Wct);
  dim3 pg((N + 63) / 64, 2);
  pgemm_kernel<<<pg, 256, 0, stream>>>(nrepb, Wrt, Wct, b, Pr, Pc, N);
  egemm_kernel<<<(E + 63) / 64, 256, 0, stream>>>(ei, ea, Weat, Pr, Pc, outE, E);
}